// Round 1
// baseline (2106.583 us; speedup 1.0000x reference)
//
#include <hip/hip_runtime.h>
#include <math.h>

#define N_NODES 20000
#define N_EDGES 4000
#define IN_DIM 128
#define OUT_DIMC 64
#define NUM_HEADS 8
#define HEAD_DIM 8
#define ALPHA 0.2f

// ---------------- workspace layout (floats) ----------------
// Xh    : [N,64]    off 0          size 1,280,000
// s     : [N,8]     off 1,280,000  size   160,000
// hm    : [8] uint  off 1,440,000  size         8  (+8 pad)
// Y     : [N,72]    off 1,440,016  size 1,440,000  (Y[n][0..7]=expn, Y[n][8+d]=expn*Xh)
// accum : [E,72]    off 2,880,016  size   288,000  ([e][0..7]=denom, [e][8+d]=num)
// agg   : [E,64]    off 3,168,016  size   256,000
// total 3,424,016 floats = 13.7 MB

__device__ __forceinline__ unsigned enc_f(float f) {
    unsigned u = __float_as_uint(f);
    return (u >> 31) ? ~u : (u | 0x80000000u);
}
__device__ __forceinline__ float dec_f(unsigned e) {
    return (e >> 31) ? __uint_as_float(e ^ 0x80000000u) : __uint_as_float(~e);
}

// init accum=0, hm=enc(-inf)
__global__ void k_init(float* __restrict__ accum, unsigned* __restrict__ hm) {
    int i = blockIdx.x * blockDim.x + threadIdx.x;
    if (i < N_EDGES * 72) accum[i] = 0.f;
    if (i < NUM_HEADS) hm[i] = 0x007FFFFFu; // enc(-inf)
}

// Xh = X @ W, s = leaky_relu(einsum(Xh, a))
// one thread per (n,d); lanes 0..63 <-> d
__global__ void k_xh_s(const float* __restrict__ X, const float* __restrict__ W,
                       const float* __restrict__ att,
                       float* __restrict__ Xh, float* __restrict__ s) {
    int t = blockIdx.x * blockDim.x + threadIdx.x;
    int n = t >> 6;
    int d = t & 63;
    if (n >= N_NODES) return;
    const float* x = X + n * IN_DIM;
    float acc = 0.f;
#pragma unroll 8
    for (int k = 0; k < IN_DIM; k++) acc += x[k] * W[k * OUT_DIMC + d];
    Xh[n * OUT_DIMC + d] = acc;
    int h = d >> 3, j = d & 7;
    float av = att[h * 16 + j] + att[h * 16 + 8 + j];
    float v = acc * av;
    v += __shfl_xor(v, 1, 64);
    v += __shfl_xor(v, 2, 64);
    v += __shfl_xor(v, 4, 64);
    if (j == 0) {
        s[n * NUM_HEADS + h] = (v >= 0.f) ? v : ALPHA * v;
    }
}

// global per-head max of s
__global__ void k_headmax(const float* __restrict__ s, unsigned* __restrict__ hm) {
    __shared__ unsigned sm[NUM_HEADS];
    int t = blockIdx.x * blockDim.x + threadIdx.x;
    if (threadIdx.x < NUM_HEADS) sm[threadIdx.x] = 0x007FFFFFu;
    __syncthreads();
    const int total = N_NODES * NUM_HEADS;
    const int stride = gridDim.x * blockDim.x; // multiple of 8 -> h fixed per thread
    float mx = -__builtin_inff();
    for (int i = t; i < total; i += stride) mx = fmaxf(mx, s[i]);
    atomicMax(&sm[t & 7], enc_f(mx));
    __syncthreads();
    if (threadIdx.x < NUM_HEADS) atomicMax(&hm[threadIdx.x], sm[threadIdx.x]);
}

// Y[n][0..7] = expn[n,h]; Y[n][8+d] = expn * Xh
__global__ void k_expn(const float* __restrict__ Xh, const float* __restrict__ s,
                       const unsigned* __restrict__ hm, float* __restrict__ Y) {
    int t = blockIdx.x * blockDim.x + threadIdx.x;
    int n = t >> 6, d = t & 63;
    if (n >= N_NODES) return;
    int h = d >> 3;
    float e = expf(s[n * NUM_HEADS + h] - dec_f(hm[h]));
    float xh = Xh[n * OUT_DIMC + d];
    Y[n * 72 + 8 + d] = e * xh;
    if ((d & 7) == 0) Y[n * 72 + h] = e;
}

// pass 1: accum[e][0..71] += sum_n mask[n,e] * Y[n][0..71]
// lanes over e (coalesced H), loop n within chunk, Y row wave-uniform
#define NCHUNK 32
#define CHSZ 625
__global__ void __launch_bounds__(256) k_pass1(const int* __restrict__ H,
                                               const float* __restrict__ Y,
                                               float* __restrict__ accum) {
    int e = blockIdx.x * blockDim.x + threadIdx.x;
    bool valid = (e < N_EDGES);
    int ec = valid ? e : 0;
    int n0 = blockIdx.y * CHSZ;
    int n1 = n0 + CHSZ;
    if (n1 > N_NODES) n1 = N_NODES;
    float acc[72];
#pragma unroll
    for (int j = 0; j < 72; j++) acc[j] = 0.f;
    const int* hp = H + ec;
    for (int n = n0; n < n1; n++) {
        int mv = hp[n * N_EDGES];
        float m = (mv > 0) ? 1.0f : 0.0f;
        const float4* y4 = (const float4*)(Y + n * 72);
#pragma unroll
        for (int j = 0; j < 18; j++) {
            float4 v = y4[j];
            acc[4 * j + 0] += m * v.x;
            acc[4 * j + 1] += m * v.y;
            acc[4 * j + 2] += m * v.z;
            acc[4 * j + 3] += m * v.w;
        }
    }
    if (valid) {
#pragma unroll
        for (int j = 0; j < 72; j++) atomicAdd(&accum[e * 72 + j], acc[j]);
    }
}

// agg[e][d] = denom>0 ? num/denom : 0
__global__ void k_agg(const float* __restrict__ accum, float* __restrict__ agg) {
    int t = blockIdx.x * blockDim.x + threadIdx.x;
    if (t >= N_EDGES * 64) return;
    int e = t >> 6, d = t & 63;
    int h = d >> 3;
    float den = accum[e * 72 + h];
    float num = accum[e * 72 + 8 + d];
    agg[t] = (den > 0.f) ? num / den : 0.f;
}

// pass 2: out[n][d] = sum_e mask[n,e] * agg[e][d] + bias[d]
// block: 64 rows x 64 cols, H tile staged through LDS (transpose fix)
__global__ void __launch_bounds__(256) k_pass2(const int* __restrict__ H,
                                               const float* __restrict__ agg,
                                               const float* __restrict__ bias,
                                               float* __restrict__ out) {
    __shared__ float mt[64][68]; // stride 68 floats = 272B, 16B-aligned rows
    int n0 = blockIdx.x * 64;
    int t = threadIdx.x;
    int d = t & 63;
    int wg = t >> 6; // 0..3
    float acc[16];
#pragma unroll
    for (int i = 0; i < 16; i++) acc[i] = 0.f;

    for (int e0 = 0; e0 < N_EDGES; e0 += 64) {
        // cooperative tile load: row r = wg + 4*i, col c = d
        int c = d;
#pragma unroll
        for (int i = 0; i < 16; i++) {
            int r = wg + 4 * i;
            int n = n0 + r;
            int ee = e0 + c;
            float m = 0.f;
            if (n < N_NODES && ee < N_EDGES) m = (H[n * N_EDGES + ee] > 0) ? 1.f : 0.f;
            mt[r][c] = m;
        }
        __syncthreads();

        if (e0 + 64 <= N_EDGES) {
            for (int ee = 0; ee < 64; ee += 4) {
                float a0 = agg[(e0 + ee + 0) * 64 + d];
                float a1 = agg[(e0 + ee + 1) * 64 + d];
                float a2 = agg[(e0 + ee + 2) * 64 + d];
                float a3 = agg[(e0 + ee + 3) * 64 + d];
#pragma unroll
                for (int i = 0; i < 16; i++) {
                    int r = wg * 16 + i;
                    float4 mm = *(const float4*)&mt[r][ee];
                    acc[i] += mm.x * a0 + mm.y * a1 + mm.z * a2 + mm.w * a3;
                }
            }
        } else {
            for (int ee = 0; ee < 64; ee++) {
                int eg = (e0 + ee < N_EDGES) ? (e0 + ee) : 0;
                float a0 = agg[eg * 64 + d];
#pragma unroll
                for (int i = 0; i < 16; i++) acc[i] += mt[wg * 16 + i][ee] * a0;
            }
        }
        __syncthreads();
    }

    float b = bias[d];
#pragma unroll
    for (int i = 0; i < 16; i++) {
        int n = n0 + wg * 16 + i;
        if (n < N_NODES) out[n * 64 + d] = acc[i] + b;
    }
}

extern "C" void kernel_launch(void* const* d_in, const int* in_sizes, int n_in,
                              void* d_out, int out_size, void* d_ws, size_t ws_size,
                              hipStream_t stream) {
    const float* X = (const float*)d_in[0];
    const int* H = (const int*)d_in[1];
    const float* W = (const float*)d_in[2];
    const float* att = (const float*)d_in[3];
    const float* bias = (const float*)d_in[4];
    float* out = (float*)d_out;

    float* ws = (float*)d_ws;
    float* Xh = ws;
    float* s = ws + 1280000;
    unsigned* hm = (unsigned*)(ws + 1440000);
    float* Y = ws + 1440016;
    float* accum = ws + 2880016;
    float* agg = ws + 3168016;

    k_init<<<(N_EDGES * 72 + 255) / 256, 256, 0, stream>>>(accum, hm);
    k_xh_s<<<(N_NODES * 64) / 256, 256, 0, stream>>>(X, W, att, Xh, s);
    k_headmax<<<64, 256, 0, stream>>>(s, hm);
    k_expn<<<(N_NODES * 64) / 256, 256, 0, stream>>>(Xh, s, hm, Y);
    {
        dim3 g((N_EDGES + 255) / 256, NCHUNK);
        k_pass1<<<g, 256, 0, stream>>>(H, Y, accum);
    }
    k_agg<<<(N_EDGES * 64) / 256, 256, 0, stream>>>(accum, agg);
    k_pass2<<<(N_NODES + 63) / 64, 256, 0, stream>>>(H, agg, bias, out);
}

// Round 2
// 2065.390 us; speedup vs baseline: 1.0199x; 1.0199x over previous
//
#include <hip/hip_runtime.h>
#include <math.h>

#define N_NODES 20000
#define N_EDGES 4000
#define IN_DIM 128
#define OUT_DIMC 64
#define NUM_HEADS 8
#define ALPHA 0.2f

#define HB_W 64     // u64 words per Hb row (e-bits): 64*64 = 4096 >= 4000
#define HBT_W 320   // u64 words per HbT row (n-bits): 313 used, padded to 320

// ---------- workspace layout (bytes) ----------
// Hb   : u64 [20000][64]   off 0           10,240,000
// HbT  : u64 [4000][320]   off 10,240,000  10,240,000
// Xh   : f32 [20000][64]   off 20,480,000   5,120,000
// s    : f32 [20000][8]    off 25,600,000     640,000
// expn : f32 [20000][8]    off 26,240,000     640,000
// Yv   : f32 [20000][64]   off 26,880,000   5,120,000
// num  : f32 [4000][64]    off 32,000,000   1,024,000   (zeroed, atomic target)
// den  : f32 [4000][8]     off 33,024,000     128,000   (zeroed, atomic target)
// acc2 : f32 [20000][64]   off 33,152,000   5,120,000   (zeroed, atomic target)
// agg  : f32 [4000][64]    off 38,272,000   1,024,000
// hm   : u32 [8]           off 39,296,000          32
// total ~39.3 MB

__device__ __forceinline__ unsigned enc_f(float f) {
    unsigned u = __float_as_uint(f);
    return (u >> 31) ? ~u : (u | 0x80000000u);
}
__device__ __forceinline__ float dec_f(unsigned e) {
    return (e >> 31) ? __uint_as_float(e ^ 0x80000000u) : __uint_as_float(~e);
}

// zero the atomic accumulators (num|den|acc2 contiguous: 1,568,000 floats), init hm
__global__ void k_init(float* __restrict__ z, unsigned* __restrict__ hm) {
    int i = blockIdx.x * blockDim.x + threadIdx.x;
    if (i < 1568000) z[i] = 0.f;
    if (i < NUM_HEADS) hm[i] = 0x007FFFFFu; // enc(-inf)
}

// bitpack H: wave per node row, ballot over 64 e's per word-pair
__global__ void __launch_bounds__(256) k_pack(const int* __restrict__ H,
                                              unsigned long long* __restrict__ Hb) {
    int wq = threadIdx.x >> 6;
    int lane = threadIdx.x & 63;
    int n = blockIdx.x * 4 + wq;
    const int* hrow = H + (size_t)n * N_EDGES;
    unsigned long long* brow = Hb + (size_t)n * HB_W;
#pragma unroll 4
    for (int c = 0; c < HB_W; c++) {
        int e = c * 64 + lane;
        bool p = false;
        if (e < N_EDGES) p = hrow[e] > 0;
        unsigned long long b = __ballot(p);
        if (lane == 0) brow[c] = b;
    }
}

// 64x64 bit-tile transpose: Hb[n][e-bits] -> HbT[e][n-bits]
__global__ void k_trans(const unsigned long long* __restrict__ Hb,
                        unsigned long long* __restrict__ HbT) {
    __shared__ unsigned long long tile[64];
    int r = threadIdx.x;           // 0..63
    int n0 = blockIdx.x * 64;
    int et = blockIdx.y;           // e-word index 0..62
    int n = n0 + r;
    tile[r] = (n < N_NODES) ? Hb[(size_t)n * HB_W + et] : 0ull;
    __syncthreads();
    int c = r;
    int e = et * 64 + c;
    if (e < N_EDGES) {
        unsigned long long out = 0ull;
        const unsigned* t32 = (const unsigned*)tile;
        unsigned sh = c & 31u;
        int sel = (c >> 5);
#pragma unroll 8
        for (int rr = 0; rr < 64; rr++) {
            unsigned w = t32[rr * 2 + sel];
            out |= (unsigned long long)((w >> sh) & 1u) << rr;
        }
        HbT[(size_t)e * HBT_W + blockIdx.x] = out;
    }
}

// Xh = X @ W ; s = leaky_relu(Xh . a)
__global__ void k_xh_s(const float* __restrict__ X, const float* __restrict__ W,
                       const float* __restrict__ att,
                       float* __restrict__ Xh, float* __restrict__ s) {
    int t = blockIdx.x * blockDim.x + threadIdx.x;
    int n = t >> 6;
    int d = t & 63;
    if (n >= N_NODES) return;
    const float* x = X + (size_t)n * IN_DIM;
    float acc = 0.f;
#pragma unroll 8
    for (int k = 0; k < IN_DIM; k++) acc += x[k] * W[k * OUT_DIMC + d];
    Xh[(size_t)n * OUT_DIMC + d] = acc;
    int h = d >> 3, j = d & 7;
    float av = att[h * 16 + j] + att[h * 16 + 8 + j];
    float v = acc * av;
    v += __shfl_xor(v, 1, 64);
    v += __shfl_xor(v, 2, 64);
    v += __shfl_xor(v, 4, 64);
    if (j == 0) s[n * NUM_HEADS + h] = (v >= 0.f) ? v : ALPHA * v;
}

__global__ void k_headmax(const float* __restrict__ s, unsigned* __restrict__ hm) {
    __shared__ unsigned sm[NUM_HEADS];
    int t = blockIdx.x * blockDim.x + threadIdx.x;
    if (threadIdx.x < NUM_HEADS) sm[threadIdx.x] = 0x007FFFFFu;
    __syncthreads();
    const int total = N_NODES * NUM_HEADS;
    const int stride = gridDim.x * blockDim.x;
    float mx = -__builtin_inff();
    for (int i = t; i < total; i += stride) mx = fmaxf(mx, s[i]);
    atomicMax(&sm[t & 7], enc_f(mx));
    __syncthreads();
    if (threadIdx.x < NUM_HEADS) atomicMax(&hm[threadIdx.x], sm[threadIdx.x]);
}

// expn[n][h] = exp(s-max) ; Yv[n][d] = expn * Xh
__global__ void k_expn(const float* __restrict__ Xh, const float* __restrict__ s,
                       const unsigned* __restrict__ hm,
                       float* __restrict__ expn, float* __restrict__ Yv) {
    int t = blockIdx.x * blockDim.x + threadIdx.x;
    int n = t >> 6, d = t & 63;
    if (n >= N_NODES) return;
    int h = d >> 3;
    float e = expf(s[n * NUM_HEADS + h] - dec_f(hm[h]));
    Yv[(size_t)n * OUT_DIMC + d] = e * Xh[(size_t)n * OUT_DIMC + d];
    if ((d & 7) == 0) expn[n * NUM_HEADS + h] = e;
}

// den[e][h] += sum_n bit(n,e) * expn[n][h]; wave per 64-e tile, lanes over e
__global__ void __launch_bounds__(256) k_den(const unsigned long long* __restrict__ Hb,
                                             const float* __restrict__ expn,
                                             float* __restrict__ den) {
    int wq = threadIdx.x >> 6;
    int lane = threadIdx.x & 63;
    int et = blockIdx.x * 4 + wq;          // e-word 0..63
    int n0 = blockIdx.y * 1000;
    float acc[8];
#pragma unroll
    for (int h = 0; h < 8; h++) acc[h] = 0.f;
    for (int n = n0; n < n0 + 1000; n++) {
        unsigned long long w = Hb[(size_t)n * HB_W + et];
        float m = (float)((unsigned)((w >> lane) & 1ull));
        const float4* er = (const float4*)(expn + n * NUM_HEADS);
        float4 e0 = er[0], e1 = er[1];
        acc[0] += m * e0.x; acc[1] += m * e0.y; acc[2] += m * e0.z; acc[3] += m * e0.w;
        acc[4] += m * e1.x; acc[5] += m * e1.y; acc[6] += m * e1.z; acc[7] += m * e1.w;
    }
    int e = et * 64 + lane;
    if (e < N_EDGES) {
#pragma unroll
        for (int h = 0; h < 8; h++) atomicAdd(&den[e * NUM_HEADS + h], acc[h]);
    }
}

// C[i][j] += sum_k bit(i,k) * V[k][j]   (j = 0..63)
// block tile: 128 i x 64 j; thread: 2 i x 16 j; K-split over grid.y, atomic out.
__global__ void __launch_bounds__(256) k_bitgemm(const unsigned long long* __restrict__ bits,
                                                 int bitsStride, int I,
                                                 const float* __restrict__ V, int K,
                                                 int kPerSplit,
                                                 float* __restrict__ Cacc) {
    __shared__ float Vt[64 * 64];
    int t = threadIdx.x;
    int jg = t & 3;            // j0 = jg*16
    int ig = t >> 2;           // i = iBase + ig*2 + {0,1}
    int j0 = jg * 16;
    int i0 = blockIdx.x * 128 + ig * 2;
    int k0s = blockIdx.y * kPerSplit;
    int k1s = k0s + kPerSplit;
    if (k1s > K) k1s = K;

    float acc[2][16];
#pragma unroll
    for (int i = 0; i < 2; i++)
#pragma unroll
        for (int j = 0; j < 16; j++) acc[i][j] = 0.f;

    bool v0 = (i0 + 0) < I, v1 = (i0 + 1) < I;
    const unsigned long long* brow0 = bits + (size_t)(v0 ? i0 + 0 : 0) * bitsStride;
    const unsigned long long* brow1 = bits + (size_t)(v1 ? i0 + 1 : 0) * bitsStride;
    const float4* V4 = (const float4*)V;
    float4* Vt4 = (float4*)Vt;

    for (int k0 = k0s; k0 < k1s; k0 += 64) {
        __syncthreads();
#pragma unroll
        for (int q = 0; q < 4; q++) {
            int f4 = t + q * 256;          // 0..1023
            int kr = f4 >> 4;
            int c4 = f4 & 15;
            float4 val = make_float4(0.f, 0.f, 0.f, 0.f);
            if (k0 + kr < k1s) val = V4[(size_t)(k0 + kr) * 16 + c4];
            Vt4[f4] = val;
        }
        __syncthreads();
        int cw = k0 >> 6;
        unsigned long long w0 = v0 ? brow0[cw] : 0ull;
        unsigned long long w1 = v1 ? brow1[cw] : 0ull;
        // bits past k1s are harmless: V rows there staged as zero
#pragma unroll 2
        for (int half = 0; half < 2; half++) {
            unsigned u0 = (unsigned)(w0 >> (half * 32));
            unsigned u1 = (unsigned)(w1 >> (half * 32));
            const float* vh = Vt + (half * 32) * 64 + j0;
#pragma unroll 8
            for (int kk = 0; kk < 32; kk++) {
                float m0 = (float)(u0 & 1u); u0 >>= 1u;
                float m1 = (float)(u1 & 1u); u1 >>= 1u;
                const float4* row = (const float4*)(vh + kk * 64);
                float4 a0 = row[0], a1 = row[1], a2 = row[2], a3 = row[3];
                float av[16] = {a0.x, a0.y, a0.z, a0.w, a1.x, a1.y, a1.z, a1.w,
                                a2.x, a2.y, a2.z, a2.w, a3.x, a3.y, a3.z, a3.w};
#pragma unroll
                for (int j = 0; j < 16; j++) {
                    acc[0][j] += m0 * av[j];
                    acc[1][j] += m1 * av[j];
                }
            }
        }
    }

    if (v0) {
#pragma unroll
        for (int j = 0; j < 16; j++) atomicAdd(&Cacc[(size_t)(i0 + 0) * 64 + j0 + j], acc[0][j]);
    }
    if (v1) {
#pragma unroll
        for (int j = 0; j < 16; j++) atomicAdd(&Cacc[(size_t)(i0 + 1) * 64 + j0 + j], acc[1][j]);
    }
}

// agg = num/den (guarded)
__global__ void k_agg(const float* __restrict__ num, const float* __restrict__ den,
                      float* __restrict__ agg) {
    int t = blockIdx.x * blockDim.x + threadIdx.x;
    if (t >= N_EDGES * 64) return;
    int e = t >> 6, d = t & 63;
    int h = d >> 3;
    float dn = den[e * NUM_HEADS + h];
    agg[t] = (dn > 0.f) ? num[t] / dn : 0.f;
}

// out = acc2 + bias
__global__ void k_final(const float* __restrict__ acc2, const float* __restrict__ bias,
                        float* __restrict__ out) {
    int t = blockIdx.x * blockDim.x + threadIdx.x;
    if (t >= N_NODES * 64) return;
    out[t] = acc2[t] + bias[t & 63];
}

extern "C" void kernel_launch(void* const* d_in, const int* in_sizes, int n_in,
                              void* d_out, int out_size, void* d_ws, size_t ws_size,
                              hipStream_t stream) {
    const float* X = (const float*)d_in[0];
    const int* H = (const int*)d_in[1];
    const float* W = (const float*)d_in[2];
    const float* att = (const float*)d_in[3];
    const float* bias = (const float*)d_in[4];
    float* out = (float*)d_out;

    char* ws = (char*)d_ws;
    unsigned long long* Hb = (unsigned long long*)(ws + 0);
    unsigned long long* HbT = (unsigned long long*)(ws + 10240000);
    float* Xh   = (float*)(ws + 20480000);
    float* s    = (float*)(ws + 25600000);
    float* expn = (float*)(ws + 26240000);
    float* Yv   = (float*)(ws + 26880000);
    float* num  = (float*)(ws + 32000000);
    float* den  = (float*)(ws + 33024000);
    float* acc2 = (float*)(ws + 33152000);
    float* agg  = (float*)(ws + 38272000);
    unsigned* hm = (unsigned*)(ws + 39296000);

    k_init<<<6125, 256, 0, stream>>>(num, hm);  // num|den|acc2 contiguous
    k_pack<<<5000, 256, 0, stream>>>(H, Hb);
    k_trans<<<dim3(313, 63), 64, 0, stream>>>(Hb, HbT);
    k_xh_s<<<5000, 256, 0, stream>>>(X, W, att, Xh, s);
    k_headmax<<<64, 256, 0, stream>>>(s, hm);
    k_expn<<<5000, 256, 0, stream>>>(Xh, s, hm, expn, Yv);
    k_den<<<dim3(16, 20), 256, 0, stream>>>(Hb, expn, den);
    // num[E,64] = H^T @ Yv : bits=HbT (stride 320), I=4000, K=20000, 32 splits of 640
    k_bitgemm<<<dim3(32, 32), 256, 0, stream>>>(HbT, HBT_W, N_EDGES, Yv, N_NODES, 640, num);
    k_agg<<<1000, 256, 0, stream>>>(num, den, agg);
    // acc2[N,64] = H @ agg : bits=Hb (stride 64), I=20000, K=4000, 8 splits of 512
    k_bitgemm<<<dim3(157, 8), 256, 0, stream>>>(Hb, HB_W, N_NODES, agg, N_EDGES, 512, acc2);
    k_final<<<5000, 256, 0, stream>>>(acc2, bias, out);
}

// Round 3
// 671.425 us; speedup vs baseline: 3.1375x; 3.0761x over previous
//
#include <hip/hip_runtime.h>
#include <math.h>

#define N_NODES 20000
#define N_EDGES 4000
#define IN_DIM 128
#define OUT_DIMC 64
#define NUM_HEADS 8
#define ALPHA 0.2f

#define HB_W 64      // u64 words per Hb row (e-bits): 64*64 = 4096 >= 4000
#define HBT_W 320    // u64 words per HbT row (n-bits): 20480 bits
#define KPAD1 20480  // padded K for pass1 (nodes)
#define KPAD2 4096   // padded K for pass2 (edges)
#define IPAD1 4032   // 63*64
#define IPAD2 20032  // 313*64
#define SPLITS1 8
#define SPLITS2 2

typedef float f32x4 __attribute__((ext_vector_type(4)));
typedef __bf16 bf16x8 __attribute__((ext_vector_type(8)));

// ---------- workspace layout (bytes) ----------
// Hb   : u64 [20000][64]     @ 0            10,240,000
// HbT  : u64 [4000][320]     @ 10,240,000   10,240,000
// VtT1 : bf16 [80][20480]    @ 20,480,000    3,276,800  (rows 0-63: (expn*Xh)^T, 64-71: expn^T, 72-79: 0)
// VtT2 : bf16 [64][4096]     @ 23,756,800      524,288  (agg^T, zero-padded)
// agg  : f32 [4000][64]      @ 24,281,088    1,024,000
// hm   : u32 [8]             @ 25,305,088           32
// Xh   : f32 [20000][64]     @ 25,305,600    5,120,000  \
// s    : f32 [20000][8]      @ 30,425,600      640,000   | dead before P written;
// expn : f32 [20000][8]      @ 31,065,600      640,000   | P aliases this region
// Yv   : f32 [20000][64]     @ 31,705,600    5,120,000  /
// P    : f32 partials        @ 25,305,600   10,321,920  (P1: 8x4032x80; P2: 2x20032x64)
// total 36.9 MB

__device__ __forceinline__ unsigned enc_f(float f) {
    unsigned u = __float_as_uint(f);
    return (u >> 31) ? ~u : (u | 0x80000000u);
}
__device__ __forceinline__ float dec_f(unsigned e) {
    return (e >> 31) ? __uint_as_float(e ^ 0x80000000u) : __uint_as_float(~e);
}
__device__ __forceinline__ unsigned short f2b(float f) {  // fp32 -> bf16 RNE, bit-level
    unsigned u = __float_as_uint(f);
    return (unsigned short)((u + 0x7FFFu + ((u >> 16) & 1u)) >> 16);
}

// bitpack H: wave per node row
__global__ void __launch_bounds__(256) k_pack(const int* __restrict__ H,
                                              unsigned long long* __restrict__ Hb) {
    int wq = threadIdx.x >> 6;
    int lane = threadIdx.x & 63;
    int n = blockIdx.x * 4 + wq;
    const int* hrow = H + (size_t)n * N_EDGES;
    unsigned long long* brow = Hb + (size_t)n * HB_W;
#pragma unroll 4
    for (int c = 0; c < HB_W; c++) {
        int e = c * 64 + lane;
        bool p = false;
        if (e < N_EDGES) p = hrow[e] > 0;
        unsigned long long b = __ballot(p);
        if (lane == 0) brow[c] = b;
    }
}

// 64x64 bit-tile transpose: Hb[n][e-bits] -> HbT[e][n-bits]
__global__ void k_trans(const unsigned long long* __restrict__ Hb,
                        unsigned long long* __restrict__ HbT) {
    __shared__ unsigned long long tile[64];
    int r = threadIdx.x;
    int n0 = blockIdx.x * 64;
    int et = blockIdx.y;
    int n = n0 + r;
    tile[r] = (n < N_NODES) ? Hb[(size_t)n * HB_W + et] : 0ull;
    __syncthreads();
    int c = r;
    int e = et * 64 + c;
    if (e < N_EDGES) {
        unsigned long long out = 0ull;
        const unsigned* t32 = (const unsigned*)tile;
        unsigned sh = c & 31u;
        int sel = (c >> 5);
#pragma unroll 8
        for (int rr = 0; rr < 64; rr++) {
            unsigned w = t32[rr * 2 + sel];
            out |= (unsigned long long)((w >> sh) & 1u) << rr;
        }
        HbT[(size_t)e * HBT_W + blockIdx.x] = out;
    }
}

// Xh = X @ W ; s = leaky_relu(Xh . a)
__global__ void k_xh_s(const float* __restrict__ X, const float* __restrict__ W,
                       const float* __restrict__ att,
                       float* __restrict__ Xh, float* __restrict__ s) {
    int t = blockIdx.x * blockDim.x + threadIdx.x;
    int n = t >> 6;
    int d = t & 63;
    if (n >= N_NODES) return;
    const float* x = X + (size_t)n * IN_DIM;
    float acc = 0.f;
#pragma unroll 8
    for (int k = 0; k < IN_DIM; k++) acc += x[k] * W[k * OUT_DIMC + d];
    Xh[(size_t)n * OUT_DIMC + d] = acc;
    int h = d >> 3, j = d & 7;
    float av = att[h * 16 + j] + att[h * 16 + 8 + j];
    float v = acc * av;
    v += __shfl_xor(v, 1, 64);
    v += __shfl_xor(v, 2, 64);
    v += __shfl_xor(v, 4, 64);
    if (j == 0) s[n * NUM_HEADS + h] = (v >= 0.f) ? v : ALPHA * v;
}

// per-head max (hm pre-zeroed; enc() of any finite float > 0)
__global__ void k_headmax(const float* __restrict__ s, unsigned* __restrict__ hm) {
    __shared__ unsigned sm[NUM_HEADS];
    int t = blockIdx.x * blockDim.x + threadIdx.x;
    if (threadIdx.x < NUM_HEADS) sm[threadIdx.x] = 0u;
    __syncthreads();
    const int total = N_NODES * NUM_HEADS;
    const int stride = gridDim.x * blockDim.x;
    float mx = -__builtin_inff();
    for (int i = t; i < total; i += stride) mx = fmaxf(mx, s[i]);
    atomicMax(&sm[t & 7], enc_f(mx));
    __syncthreads();
    if (threadIdx.x < NUM_HEADS) atomicMax(&hm[threadIdx.x], sm[threadIdx.x]);
}

// expn[n][h] = exp(s-max) ; Yv[n][d] = expn * Xh
__global__ void k_expn(const float* __restrict__ Xh, const float* __restrict__ s,
                       const unsigned* __restrict__ hm,
                       float* __restrict__ expn, float* __restrict__ Yv) {
    int t = blockIdx.x * blockDim.x + threadIdx.x;
    int n = t >> 6, d = t & 63;
    if (n >= N_NODES) return;
    int h = d >> 3;
    float e = expf(s[n * NUM_HEADS + h] - dec_f(hm[h]));
    Yv[(size_t)n * OUT_DIMC + d] = e * Xh[(size_t)n * OUT_DIMC + d];
    if ((d & 7) == 0) expn[n * NUM_HEADS + h] = e;
}

// transpose f32 [rowsIn][64] -> bf16 [64][Kpad] (zero-padded); grid = Kpad/64
__global__ void __launch_bounds__(256) k_transF(const float* __restrict__ src, int rowsIn,
                                                unsigned short* __restrict__ dst, int Kpad) {
    __shared__ float tl[64][68];
    int t = threadIdx.x;
    int n0 = blockIdx.x * 64;
    int r = t >> 2, s4 = t & 3;
#pragma unroll
    for (int m = 0; m < 4; m++) {
        int cbase = s4 * 16 + m * 4;
        float4 v = make_float4(0.f, 0.f, 0.f, 0.f);
        if (n0 + r < rowsIn) v = *(const float4*)(src + (size_t)(n0 + r) * 64 + cbase);
        tl[r][cbase] = v.x; tl[r][cbase + 1] = v.y; tl[r][cbase + 2] = v.z; tl[r][cbase + 3] = v.w;
    }
    __syncthreads();
    int d = t >> 2;
    unsigned short buf[16];
#pragma unroll
    for (int j = 0; j < 16; j++) buf[j] = f2b(tl[s4 * 16 + j][d]);
    uint4* o = (uint4*)(dst + (size_t)d * Kpad + n0 + s4 * 16);
    o[0] = *(uint4*)&buf[0];
    o[1] = *(uint4*)&buf[8];
}

// expn^T into VtT1 rows 64..79 (72..79 zero); grid 320
__global__ void __launch_bounds__(256) k_transE(const float* __restrict__ expn,
                                                unsigned short* __restrict__ VtT1) {
    int n = blockIdx.x * 64 + (threadIdx.x & 63);
    int h0 = threadIdx.x >> 6;
#pragma unroll
    for (int p = 0; p < 4; p++) {
        int row = 64 + h0 + p * 4;
        float v = 0.f;
        if (row < 72 && n < N_NODES) v = expn[(size_t)n * NUM_HEADS + (row - 64)];
        VtT1[(size_t)row * KPAD1 + n] = f2b(v);
    }
}

__device__ __forceinline__ bf16x8 expand8(unsigned b) {
    union { uint4 u; bf16x8 v; } cv;
    cv.u.x = ((b & 1u)   ? 0x3F80u : 0u) | ((b & 2u)   ? 0x3F800000u : 0u);
    cv.u.y = ((b & 4u)   ? 0x3F80u : 0u) | ((b & 8u)   ? 0x3F800000u : 0u);
    cv.u.z = ((b & 16u)  ? 0x3F80u : 0u) | ((b & 32u)  ? 0x3F800000u : 0u);
    cv.u.w = ((b & 64u)  ? 0x3F80u : 0u) | ((b & 128u) ? 0x3F800000u : 0u);
    return cv.v;
}
__device__ __forceinline__ bf16x8 ldsread(const unsigned short* p) {
    union { uint4 u; bf16x8 v; } cv;
    cv.u = *(const uint4*)p;
    return cv.v;
}

// C[I, NCT*16] = bits[I, K] @ V[K, NCT*16] via mfma_f32_16x16x32_bf16.
// V given transposed: Vg = bf16 [NCT*16][Kpad]. K-split over grid.y -> disjoint partials.
// Block: 4 waves x 16 rows = 64 rows; wave loops NCT col-tiles (B shared via LDS).
template <int NCT>
__global__ void __launch_bounds__(256) k_mm(const unsigned long long* __restrict__ bits,
                                            int stride, int I,
                                            const unsigned short* __restrict__ Vg,
                                            int Kpad, int kPerSplit,
                                            float* __restrict__ P, int Ipad) {
    __shared__ __align__(16) unsigned short Vlds[NCT * 16][72];
    const int t = threadIdx.x;
    const int l = t & 63;
    const int w = t >> 6;
    const int q = l >> 4;
    const int col = l & 15;
    const int i0 = blockIdx.x * 64;
    const int split = blockIdx.y;
    const int k0 = split * kPerSplit;
    const int k1 = k0 + kPerSplit;

    int arow = i0 + w * 16 + col;
    if (arow >= I) arow = I - 1;
    const unsigned long long* bp = bits + (size_t)arow * stride;

    f32x4 acc[NCT];
#pragma unroll
    for (int c = 0; c < NCT; c++) acc[c] = (f32x4){0.f, 0.f, 0.f, 0.f};

    for (int kc = k0; kc < k1; kc += 64) {
        __syncthreads();
        for (int ch = t; ch < NCT * 16 * 8; ch += 256) {
            int vr = ch >> 3;
            int cj = ch & 7;
            uint4 val = *(const uint4*)(Vg + (size_t)vr * Kpad + kc + cj * 8);
            *(uint4*)&Vlds[vr][cj * 8] = val;
        }
        unsigned long long wbits = bp[kc >> 6];
        __syncthreads();
        unsigned b0 = (unsigned)(wbits >> (q * 8)) & 0xFFu;
        unsigned b1 = (unsigned)(wbits >> (32 + q * 8)) & 0xFFu;
        bf16x8 a0 = expand8(b0);
        bf16x8 a1 = expand8(b1);
#pragma unroll
        for (int c = 0; c < NCT; c++) {
            bf16x8 bv0 = ldsread(&Vlds[c * 16 + col][q * 8]);
            acc[c] = __builtin_amdgcn_mfma_f32_16x16x32_bf16(a0, bv0, acc[c], 0, 0, 0);
            bf16x8 bv1 = ldsread(&Vlds[c * 16 + col][32 + q * 8]);
            acc[c] = __builtin_amdgcn_mfma_f32_16x16x32_bf16(a1, bv1, acc[c], 0, 0, 0);
        }
    }

    size_t base = (size_t)split * Ipad + i0 + w * 16;
#pragma unroll
    for (int c = 0; c < NCT; c++) {
#pragma unroll
        for (int r = 0; r < 4; r++) {
            int irow = q * 4 + r;
            P[(base + irow) * (NCT * 16) + c * 16 + col] = acc[c][r];
        }
    }
}

// agg = num/den from pass-1 partials (cols 0..63 num, 64+h den)
__global__ void k_agg(const float* __restrict__ P1, float* __restrict__ agg) {
    int t = blockIdx.x * blockDim.x + threadIdx.x;
    if (t >= N_EDGES * 64) return;
    int e = t >> 6, d = t & 63, h = d >> 3;
    float num = 0.f, den = 0.f;
#pragma unroll
    for (int sp = 0; sp < SPLITS1; sp++) {
        const float* row = P1 + ((size_t)sp * IPAD1 + e) * 80;
        num += row[d];
        den += row[64 + h];
    }
    agg[t] = (den > 0.f) ? num / den : 0.f;
}

// out = sum of pass-2 partials + bias
__global__ void k_final(const float* __restrict__ P2, const float* __restrict__ bias,
                        float* __restrict__ out) {
    int t = blockIdx.x * blockDim.x + threadIdx.x;
    if (t >= N_NODES * 64) return;
    int n = t >> 6, d = t & 63;
    float v = bias[d];
#pragma unroll
    for (int sp = 0; sp < SPLITS2; sp++) v += P2[((size_t)sp * IPAD2 + n) * 64 + d];
    out[t] = v;
}

extern "C" void kernel_launch(void* const* d_in, const int* in_sizes, int n_in,
                              void* d_out, int out_size, void* d_ws, size_t ws_size,
                              hipStream_t stream) {
    const float* X = (const float*)d_in[0];
    const int* H = (const int*)d_in[1];
    const float* W = (const float*)d_in[2];
    const float* att = (const float*)d_in[3];
    const float* bias = (const float*)d_in[4];
    float* out = (float*)d_out;

    char* ws = (char*)d_ws;
    unsigned long long* Hb  = (unsigned long long*)(ws + 0);
    unsigned long long* HbT = (unsigned long long*)(ws + 10240000);
    unsigned short* VtT1 = (unsigned short*)(ws + 20480000);
    unsigned short* VtT2 = (unsigned short*)(ws + 23756800);
    float* agg  = (float*)(ws + 24281088);
    unsigned* hm = (unsigned*)(ws + 25305088);
    float* Xh   = (float*)(ws + 25305600);
    float* s    = (float*)(ws + 30425600);
    float* expn = (float*)(ws + 31065600);
    float* Yv   = (float*)(ws + 31705600);
    float* P    = (float*)(ws + 25305600);  // aliases Xh/s/expn/Yv (dead by then)

    hipMemsetAsync(hm, 0, 32, stream);
    k_pack<<<5000, 256, 0, stream>>>(H, Hb);
    k_trans<<<dim3(313, 63), 64, 0, stream>>>(Hb, HbT);
    k_xh_s<<<5000, 256, 0, stream>>>(X, W, att, Xh, s);
    k_headmax<<<64, 256, 0, stream>>>(s, hm);
    k_expn<<<5000, 256, 0, stream>>>(Xh, s, hm, expn, Yv);
    k_transF<<<KPAD1 / 64, 256, 0, stream>>>(Yv, N_NODES, VtT1, KPAD1);
    k_transE<<<KPAD1 / 64, 256, 0, stream>>>(expn, VtT1);
    // pass 1: [4000 x 80] = HbT @ [Yv | expn | 0]
    k_mm<5><<<dim3(IPAD1 / 64, SPLITS1), 256, 0, stream>>>(HbT, HBT_W, N_EDGES, VtT1,
                                                           KPAD1, KPAD1 / SPLITS1, P, IPAD1);
    k_agg<<<1000, 256, 0, stream>>>(P, agg);
    k_transF<<<KPAD2 / 64, 256, 0, stream>>>(agg, N_EDGES, VtT2, KPAD2);
    // pass 2: [20000 x 64] = Hb @ agg
    k_mm<4><<<dim3(IPAD2 / 64, SPLITS2), 256, 0, stream>>>(Hb, HB_W, N_NODES, VtT2,
                                                           KPAD2, KPAD2 / SPLITS2, P, IPAD2);
    k_final<<<5000, 256, 0, stream>>>(P, bias, out);
}

// Round 4
// 558.958 us; speedup vs baseline: 3.7688x; 1.2012x over previous
//
#include <hip/hip_runtime.h>
#include <math.h>

#define N_NODES 20000
#define N_EDGES 4000
#define IN_DIM 128
#define NUM_HEADS 8
#define ALPHA 0.2f

#define HB_W 64      // u64 words per Hb row (e-bits): 4096 bits
#define HBT_W 320    // u64 words per HbT row (n-bits): 20480 bits
#define KPAD1 20480
#define KPAD2 4096
#define IPAD1 4096   // 16 blocks x 256 rows
#define IPAD2 20224  // 79 blocks x 256 rows
#define SPLITS1 32   // 640 k each = 5 stages of 128
#define SPLITS2 8    // 512 k each = 4 stages of 128

typedef float f32x4 __attribute__((ext_vector_type(4)));
typedef __bf16 bf16x8 __attribute__((ext_vector_type(8)));

// ---------- workspace layout (bytes) ----------
// Hb   : u64 [20000][64]   @ 0           10,240,000
// HbT  : u64 [4000][320]   @ 10,240,000  10,240,000
// VtT1 : bf16 [80][20480]  @ 20,480,000   3,276,800
// VtT2 : bf16 [64][4096]   @ 23,756,800     524,288
// expn : f32 [20000][8]    @ 24,281,088     640,000
// Yv   : f32 [20000][64]   @ 24,921,088   5,120,000
// P    : f32 partials      @ 30,041,088  41,943,040  (P1: 32x4096x80 / P2: 8x20224x64)
// total ~72 MB (d_ws poison shows 1.25 GB available)

__device__ __forceinline__ unsigned short f2b(float f) {
    unsigned u = __float_as_uint(f);
    return (unsigned short)((u + 0x7FFFu + ((u >> 16) & 1u)) >> 16);
}

// ---- bitpack H with int4 loads + LDS nibble pack; wave per row, 16 iters of 256 e ----
__global__ void __launch_bounds__(256) k_pack(const int* __restrict__ H,
                                              unsigned long long* __restrict__ Hb) {
    __shared__ unsigned char nib[4][64];
    int wq = threadIdx.x >> 6;
    int lane = threadIdx.x & 63;
    int n = blockIdx.x * 4 + wq;
    const int* hrow = H + (size_t)n * N_EDGES;
    unsigned long long* brow = Hb + (size_t)n * HB_W;
    for (int it = 0; it < 16; it++) {
        int e = it * 256 + lane * 4;
        unsigned nb = 0;
        if (e < N_EDGES) {   // e multiple of 4, row len 4000 -> e+3 in range
            int4 v = *(const int4*)(hrow + e);
            nb = (v.x > 0 ? 1u : 0u) | (v.y > 0 ? 2u : 0u) | (v.z > 0 ? 4u : 0u) | (v.w > 0 ? 8u : 0u);
        }
        __syncthreads();
        nib[wq][lane] = (unsigned char)nb;
        __syncthreads();
        if (lane < 16) {
            // word (64 e's) from 16 nibbles
            const unsigned* p = (const unsigned*)&nib[wq][lane * 16];
            unsigned long long w = 0;
#pragma unroll
            for (int c = 0; c < 4; c++) {
                unsigned u = p[c];
                unsigned b16 = (u & 0xFu) | (((u >> 8) & 0xFu) << 4) |
                               (((u >> 16) & 0xFu) << 8) | (((u >> 24) & 0xFu) << 12);
                w |= (unsigned long long)b16 << (16 * c);
            }
            brow[it * 4 + lane] = w;  // hmm: see note below
        }
    }
}
// NOTE on k_pack store index: iter covers e [it*256, it*256+256) = words it*4 .. it*4+3,
// and lane g<16 packs nibbles of lanes g*16..g*16+15 = e [it*256+g*64, +64) = word it*4+g.
// With g<16 but only 4 words per iter -> lanes 4..15 would write OOB. Fixed: only lanes<4.
// (guard applied in code below via second kernel-correct version)

// ---- corrected pack (wave handles 4 rows' worth per iter is wrong; use lanes<4) ----
__global__ void __launch_bounds__(256) k_pack2(const int* __restrict__ H,
                                               unsigned long long* __restrict__ Hb) {
    __shared__ unsigned char nib[4][64];
    int wq = threadIdx.x >> 6;
    int lane = threadIdx.x & 63;
    int n = blockIdx.x * 4 + wq;
    const int* hrow = H + (size_t)n * N_EDGES;
    unsigned long long* brow = Hb + (size_t)n * HB_W;
    for (int it = 0; it < 16; it++) {
        int e = it * 256 + lane * 4;
        unsigned nb = 0;
        if (e < N_EDGES) {
            int4 v = *(const int4*)(hrow + e);
            nb = (v.x > 0 ? 1u : 0u) | (v.y > 0 ? 2u : 0u) | (v.z > 0 ? 4u : 0u) | (v.w > 0 ? 8u : 0u);
        }
        __syncthreads();
        nib[wq][lane] = (unsigned char)nb;
        __syncthreads();
        if (lane < 4) {
            const unsigned* p = (const unsigned*)&nib[wq][lane * 16];
            unsigned long long w = 0;
#pragma unroll
            for (int c = 0; c < 4; c++) {
                unsigned u = p[c];
                unsigned b16 = (u & 0xFu) | (((u >> 8) & 0xFu) << 4) |
                               (((u >> 16) & 0xFu) << 8) | (((u >> 24) & 0xFu) << 12);
                w |= (unsigned long long)b16 << (16 * c);
            }
            brow[it * 4 + lane] = w;
        }
    }
}

// ---- ballot bit-transpose: Hb[n][e-word] -> HbT[e][n-word] ----
__global__ void __launch_bounds__(256) k_transB(const unsigned long long* __restrict__ Hb,
                                                unsigned long long* __restrict__ HbT) {
    int wq = threadIdx.x >> 6;
    int lane = threadIdx.x & 63;
    int et = blockIdx.y * 4 + wq;           // e-word 0..62
    if (et >= 63) return;
    int n0 = blockIdx.x * 64;
    int n = n0 + lane;
    unsigned long long w = (n < N_NODES) ? Hb[(size_t)n * HB_W + et] : 0ull;
    unsigned long long out = 0ull;
#pragma unroll
    for (int c = 0; c < 64; c++) {
        unsigned long long b = __ballot((w >> c) & 1ull);
        if (lane == c) out = b;
    }
    int e = et * 64 + lane;
    if (e < N_EDGES) HbT[(size_t)e * HBT_W + blockIdx.x] = out;
}

// ---- fused: Xh = X@W ; s = leaky_relu(Xh.a) ; e = exp(s) (max-shift cancels in num/den) ----
__global__ void __launch_bounds__(256) k_fused1(const float* __restrict__ X,
                                                const float* __restrict__ W,
                                                const float* __restrict__ att,
                                                float* __restrict__ expn,
                                                float* __restrict__ Yv) {
    int t = blockIdx.x * blockDim.x + threadIdx.x;
    int n = __builtin_amdgcn_readfirstlane(t >> 6);
    int d = t & 63;
    const float* x = X + (size_t)n * IN_DIM;
    float acc = 0.f;
#pragma unroll 8
    for (int k = 0; k < IN_DIM; k++) acc += x[k] * W[k * 64 + d];
    int h = d >> 3, j = d & 7;
    float av = att[h * 16 + j] + att[h * 16 + 8 + j];
    float v = acc * av;
    v += __shfl_xor(v, 1, 64);
    v += __shfl_xor(v, 2, 64);
    v += __shfl_xor(v, 4, 64);
    float s = (v >= 0.f) ? v : ALPHA * v;
    float e = expf(s);
    Yv[(size_t)n * 64 + d] = e * acc;
    if (j == 0) expn[(size_t)n * NUM_HEADS + h] = e;
}

// ---- Yv + expn -> VtT1 bf16 [80][KPAD1] transposed (rows 0-63 Yv^T, 64-71 expn^T, 72-79 zero)
__global__ void __launch_bounds__(256) k_transFE(const float* __restrict__ Yv,
                                                 const float* __restrict__ expn,
                                                 unsigned short* __restrict__ VtT1) {
    __shared__ float tl[64][65];
    int t = threadIdx.x;
    int n0 = blockIdx.x * 64;
    int r = t >> 2, s4 = t & 3;
#pragma unroll
    for (int m = 0; m < 4; m++) {
        int cbase = s4 * 16 + m * 4;
        float4 v = make_float4(0.f, 0.f, 0.f, 0.f);
        if (n0 + r < N_NODES) v = *(const float4*)(Yv + (size_t)(n0 + r) * 64 + cbase);
        tl[r][cbase] = v.x; tl[r][cbase + 1] = v.y; tl[r][cbase + 2] = v.z; tl[r][cbase + 3] = v.w;
    }
    __syncthreads();
    int d = t >> 2;
    unsigned short buf[16];
#pragma unroll
    for (int j = 0; j < 16; j++) buf[j] = f2b(tl[s4 * 16 + j][d]);
    uint4* o = (uint4*)(VtT1 + (size_t)d * KPAD1 + n0 + s4 * 16);
    o[0] = *(uint4*)&buf[0];
    o[1] = *(uint4*)&buf[8];
    // expn rows 64..79 (72..79 zero)
    int nl = t & 63;
    int rw = t >> 6;
#pragma unroll
    for (int p = 0; p < 4; p++) {
        int row = 64 + rw * 4 + p;
        float v = 0.f;
        if (row < 72 && n0 + nl < N_NODES) v = expn[(size_t)(n0 + nl) * NUM_HEADS + (row - 64)];
        VtT1[(size_t)row * KPAD1 + n0 + nl] = f2b(v);
    }
}

__device__ __forceinline__ bf16x8 expand8(unsigned b) {
    union { uint4 u; bf16x8 v; } cv;
    cv.u.x = ((b & 1u)   ? 0x3F80u : 0u) | ((b & 2u)   ? 0x3F800000u : 0u);
    cv.u.y = ((b & 4u)   ? 0x3F80u : 0u) | ((b & 8u)   ? 0x3F800000u : 0u);
    cv.u.z = ((b & 16u)  ? 0x3F80u : 0u) | ((b & 32u)  ? 0x3F800000u : 0u);
    cv.u.w = ((b & 64u)  ? 0x3F80u : 0u) | ((b & 128u) ? 0x3F800000u : 0u);
    return cv.v;
}
__device__ __forceinline__ bf16x8 ldsread(const unsigned short* p) {
    union { uint4 u; bf16x8 v; } cv;
    cv.u = *(const uint4*)p;
    return cv.v;
}

// ---- bit-mask MFMA GEMM: C[I, NCT*16] = bits[I,K] @ V[K, NCT*16]
// Wave owns 4 row-tiles (64 rows); block = 4 waves = 256 rows. 128-k stages.
// B fragment read once from LDS feeds 4 MFMAs (4x B-reuse vs R3).
template <int NCT>
__global__ void __launch_bounds__(256) k_mm(const unsigned long long* __restrict__ bits,
                                            int stride, int I,
                                            const unsigned short* __restrict__ Vg,
                                            int Kpad, int kPerSplit,
                                            float* __restrict__ P, int Ipad) {
    __shared__ __align__(16) unsigned short Vlds[NCT * 16][136];  // 128 k + 8 pad
    const int t = threadIdx.x;
    const int l = t & 63;
    const int w = t >> 6;
    const int q = l >> 4;
    const int cl = l & 15;
    const int rowbase = blockIdx.x * 256 + w * 64;
    const int k0 = blockIdx.y * kPerSplit;
    const int nstages = kPerSplit >> 7;

    const unsigned long long* bp[4];
#pragma unroll
    for (int rt = 0; rt < 4; rt++) {
        int r = rowbase + rt * 16 + cl;
        if (r >= I) r = I - 1;
        bp[rt] = bits + (size_t)r * stride;
    }

    f32x4 acc[4][NCT];
#pragma unroll
    for (int rt = 0; rt < 4; rt++)
#pragma unroll
        for (int c = 0; c < NCT; c++) acc[rt][c] = (f32x4){0.f, 0.f, 0.f, 0.f};

    for (int st = 0; st < nstages; st++) {
        int kc = k0 + st * 128;
        __syncthreads();
#pragma unroll
        for (int ch = t; ch < NCT * 256; ch += 256) {
            int vr = ch >> 4;
            int cj = ch & 15;
            uint4 val = *(const uint4*)(Vg + (size_t)vr * Kpad + kc + cj * 8);
            *(uint4*)&Vlds[vr][cj * 8] = val;
        }
        ulonglong2 wb[4];
#pragma unroll
        for (int rt = 0; rt < 4; rt++) wb[rt] = *(const ulonglong2*)(bp[rt] + (kc >> 6));
        __syncthreads();
#pragma unroll
        for (int kf = 0; kf < 4; kf++) {
            bf16x8 a[4];
#pragma unroll
            for (int rt = 0; rt < 4; rt++) {
                unsigned long long wsel = (kf < 2) ? wb[rt].x : wb[rt].y;
                unsigned byte = (unsigned)(wsel >> ((kf & 1) * 32 + q * 8)) & 0xFFu;
                a[rt] = expand8(byte);
            }
#pragma unroll
            for (int c = 0; c < NCT; c++) {
                bf16x8 bv = ldsread(&Vlds[c * 16 + cl][kf * 32 + q * 8]);
#pragma unroll
                for (int rt = 0; rt < 4; rt++)
                    acc[rt][c] = __builtin_amdgcn_mfma_f32_16x16x32_bf16(a[rt], bv, acc[rt][c], 0, 0, 0);
            }
        }
    }

    size_t base = (size_t)blockIdx.y * Ipad;
#pragma unroll
    for (int rt = 0; rt < 4; rt++)
#pragma unroll
        for (int c = 0; c < NCT; c++)
#pragma unroll
            for (int r = 0; r < 4; r++)
                P[(base + rowbase + rt * 16 + q * 4 + r) * (NCT * 16) + c * 16 + cl] = acc[rt][c][r];
}

// ---- reduce pass-1 partials, divide, write VtT2 bf16 transposed ----
__global__ void __launch_bounds__(256) k_aggT(const float* __restrict__ P1,
                                              unsigned short* __restrict__ VtT2) {
    __shared__ float tl[64][65];
    int t = threadIdx.x;
    int e0 = blockIdx.x * 64;
    int el = t >> 2, s4 = t & 3;
    int e = e0 + el;
    float num[16];
#pragma unroll
    for (int j = 0; j < 16; j++) num[j] = 0.f;
    float den0 = 0.f, den1 = 0.f;
    for (int sp = 0; sp < SPLITS1; sp++) {
        const float* row = P1 + ((size_t)sp * IPAD1 + e) * 80;
        const float4* r4 = (const float4*)(row + s4 * 16);
        float4 a = r4[0], b = r4[1], c = r4[2], d = r4[3];
        num[0] += a.x;  num[1] += a.y;  num[2] += a.z;  num[3] += a.w;
        num[4] += b.x;  num[5] += b.y;  num[6] += b.z;  num[7] += b.w;
        num[8] += c.x;  num[9] += c.y;  num[10] += c.z; num[11] += c.w;
        num[12] += d.x; num[13] += d.y; num[14] += d.z; num[15] += d.w;
        float2 dn = *(const float2*)(row + 64 + s4 * 2);
        den0 += dn.x; den1 += dn.y;
    }
#pragma unroll
    for (int j = 0; j < 16; j++) {
        float den = (j < 8) ? den0 : den1;
        float v = (e < N_EDGES && den > 0.f) ? num[j] / den : 0.f;
        tl[el][s4 * 16 + j] = v;
    }
    __syncthreads();
    int d = t >> 2;
    unsigned short buf[16];
#pragma unroll
    for (int j = 0; j < 16; j++) buf[j] = f2b(tl[s4 * 16 + j][d]);
    uint4* o = (uint4*)(VtT2 + (size_t)d * KPAD2 + e0 + s4 * 16);
    o[0] = *(uint4*)&buf[0];
    o[1] = *(uint4*)&buf[8];
}

// ---- out = sum of pass-2 partials + bias ----
__global__ void __launch_bounds__(256) k_final(const float* __restrict__ P2,
                                               const float* __restrict__ bias,
                                               float* __restrict__ out) {
    int t = blockIdx.x * blockDim.x + threadIdx.x;
    int n = t >> 6, d = t & 63;
    float v = bias[d];
#pragma unroll
    for (int sp = 0; sp < SPLITS2; sp++) v += P2[((size_t)sp * IPAD2 + n) * 64 + d];
    out[t] = v;
}

extern "C" void kernel_launch(void* const* d_in, const int* in_sizes, int n_in,
                              void* d_out, int out_size, void* d_ws, size_t ws_size,
                              hipStream_t stream) {
    const float* X = (const float*)d_in[0];
    const int* H = (const int*)d_in[1];
    const float* W = (const float*)d_in[2];
    const float* att = (const float*)d_in[3];
    const float* bias = (const float*)d_in[4];
    float* out = (float*)d_out;

    char* ws = (char*)d_ws;
    unsigned long long* Hb  = (unsigned long long*)(ws + 0);
    unsigned long long* HbT = (unsigned long long*)(ws + 10240000);
    unsigned short* VtT1 = (unsigned short*)(ws + 20480000);
    unsigned short* VtT2 = (unsigned short*)(ws + 23756800);
    float* expn = (float*)(ws + 24281088);
    float* Yv   = (float*)(ws + 24921088);
    float* P    = (float*)(ws + 30041088);

    k_pack2<<<5000, 256, 0, stream>>>(H, Hb);
    k_transB<<<dim3(313, 16), 256, 0, stream>>>(Hb, HbT);
    k_fused1<<<5000, 256, 0, stream>>>(X, W, att, expn, Yv);
    k_transFE<<<KPAD1 / 64, 256, 0, stream>>>(Yv, expn, VtT1);
    // pass 1: [4000 x 80] = HbT @ [Yv | expn | 0]
    k_mm<5><<<dim3(IPAD1 / 256, SPLITS1), 256, 0, stream>>>(HbT, HBT_W, N_EDGES, VtT1,
                                                            KPAD1, KPAD1 / SPLITS1, P, IPAD1);
    k_aggT<<<KPAD2 / 64, 256, 0, stream>>>(P, VtT2);
    // pass 2: [20000 x 64] = Hb @ agg
    k_mm<4><<<dim3(IPAD2 / 256, SPLITS2), 256, 0, stream>>>(Hb, HB_W, N_NODES, VtT2,
                                                            KPAD2, KPAD2 / SPLITS2, P, IPAD2);
    k_final<<<5000, 256, 0, stream>>>(P, bias, out);
}